// Round 4
// baseline (54.916 us; speedup 1.0000x reference)
//
#include <hip/hip_runtime.h>
#include <stdint.h>

// 4-point Hermite resampler — wave-private LDS windows staged via
// global_load_lds (direct HBM->LDS, no VGPR round-trip), zero barriers,
// counted vmcnt(2) so next-channel loads stay in flight under compute (T4).
// Wave w of 4 owns outputs [jw, jw+256); its taps span <=285 consecutive
// input floats -> stage 512 floats (2 x 1KB global_load_lds, wave-uniform
// LDS base + lane*16B global addr). Tap LDS offsets are loop-invariant per
// thread (same indices for every channel) -> hoisted; 16 ds_read_b32/iter.
// grid.y=2 splits channels for TLP (16 ch per block).

#define NW    4
#define OPW   256
#define TILE  (NW * OPW)   // 1024 outputs per block in j
#define WFL   512          // staged floats per wave window (2 KB)
#define CPB   16           // channels per block (grid.y = 32/CPB = 2)

typedef float vf4 __attribute__((ext_vector_type(4)));
typedef int   vi4 __attribute__((ext_vector_type(4)));

typedef const __attribute__((address_space(1))) uint32_t* gas_t;
typedef __attribute__((address_space(3))) uint32_t* las_t;

__device__ __forceinline__ void stage2(const float* g, float* l) {
    // lane i fetches 16B from g + i*16 -> LDS base + i*16 (linear)
    __builtin_amdgcn_global_load_lds((gas_t)g,         (las_t)l,         16, 0, 0);
    __builtin_amdgcn_global_load_lds((gas_t)(g + 256), (las_t)(l + 256), 16, 0, 0);
}

struct TapIdx { int rm1[4], r0[4], r1[4], r2[4]; };

__device__ __forceinline__ void body(
    int s, const float* __restrict__ gbase, float* op, int out_bs, int in_bs,
    float* cur, float* nxt, const TapIdx& ti, vf4 xv, bool valid, int cpb)
{
    // issue next channel's staging into the other buffer, then wait only
    // until the CURRENT buffer's 2 loads have landed (vmcnt(2) leaves the
    // 2 new loads outstanding; in-order retirement => current ones done).
    const int sn = (s + 1 < cpb) ? (s + 1) : s;   // last iter: dead restage
    stage2(gbase + (size_t)sn * (size_t)in_bs, nxt);
    asm volatile("s_waitcnt vmcnt(2)" ::: "memory");
    __builtin_amdgcn_sched_barrier(0);

    vf4 o;
    #pragma unroll
    for (int k = 0; k < 4; ++k) {
        const float ym1 = cur[ti.rm1[k]];
        const float y0f = cur[ti.r0[k]];
        const float y1f = cur[ti.r1[k]];
        const float y2f = cur[ti.r2[k]];
        const float c1 = 0.5f * (y1f - ym1);
        const float c2 = ym1 - 2.5f * y0f + 2.0f * y1f - 0.5f * y2f;
        const float c3 = 0.5f * (y2f - ym1) + 1.5f * (y0f - y1f);
        const float xw = xv[k];
        o[k] = ((c3 * xw + c2) * xw + c1) * xw + y0f;
    }
    if (valid) *(vf4*)(op + (size_t)s * (size_t)out_bs) = o;
}

__global__ __launch_bounds__(256) void hermite_async_kernel(
    const float* __restrict__ y,       // [32, in_bs]
    const float* __restrict__ x,       // [out_bs]
    const int* __restrict__ y0_idx,    // [out_bs]
    float* __restrict__ out,           // [32, out_bs]
    int out_bs, int in_bs)
{
    __shared__ float sbuf[NW][2][WFL];   // 16 KB, wave-private double buffers
    const int t    = threadIdx.x;
    const int w    = t >> 6;
    const int lane = t & 63;
    const int jw   = blockIdx.x * TILE + w * OPW;  // wave's first output
    const int j    = jw + 4 * lane;                // thread's 4 outputs at j..j+3
    const int ch0  = blockIdx.y * CPB;

    // wave-uniform staging base (floats), float4-aligned, clamped in-row
    int src = (y0_idx[min(jw, out_bs - 1)] - 1) & ~3;
    src = max(src, 0);
    src = min(src, in_bs - WFL);

    const bool valid = (j < out_bs);   // out_bs % 4 == 0, so covers j..j+3
    vf4 xv  = {0.f, 0.f, 0.f, 0.f};
    vi4 y0v = {src + 1, src + 1, src + 1, src + 1};
    if (valid) {
        xv  = *(const vf4*)(x + j);
        y0v = *(const vi4*)(y0_idx + j);
    }
    // clamped tap offsets into the window — identical for every channel
    TapIdx ti;
    #pragma unroll
    for (int k = 0; k < 4; ++k) {
        const int y0 = y0v[k];
        ti.rm1[k] = max(y0 - 1, 0) - src;
        ti.r0[k]  = y0 - src;
        ti.r1[k]  = min(y0 + 1, in_bs - 1) - src;
        ti.r2[k]  = min(y0 + 2, in_bs - 1) - src;
    }

    float* lds0 = &sbuf[w][0][0];
    float* lds1 = &sbuf[w][1][0];
    const float* gbase = y + (size_t)ch0 * (size_t)in_bs + src + 4 * lane;
    float*       op    = out + (size_t)ch0 * (size_t)out_bs + j;

    stage2(gbase, lds0);   // prologue: channel ch0 -> buffer 0

    for (int s = 0; s < CPB; s += 2) {   // static buffer parity (rule #20)
        body(s,     gbase, op, out_bs, in_bs, lds0, lds1, ti, xv, valid, CPB);
        body(s + 1, gbase, op, out_bs, in_bs, lds1, lds0, ti, xv, valid, CPB);
    }
}

extern "C" void kernel_launch(void* const* d_in, const int* in_sizes, int n_in,
                              void* d_out, int out_size, void* d_ws, size_t ws_size,
                              hipStream_t stream)
{
    const float* y   = (const float*)d_in[0];
    const float* x   = (const float*)d_in[1];
    const int*   i0  = (const int*)d_in[3];   // y0_idx
    float*       out = (float*)d_out;

    const int out_bs = in_sizes[1];           // 963380
    const int n_ch   = out_size / out_bs;     // 32
    const int in_bs  = in_sizes[0] / n_ch;    // 1048576

    dim3 grid((out_bs + TILE - 1) / TILE, n_ch / CPB, 1);   // (941, 2)
    hermite_async_kernel<<<grid, 256, 0, stream>>>(
        y, x, i0, out, out_bs, in_bs);
}

// Round 5
// 48.624 us; speedup vs baseline: 1.1294x; 1.1294x over previous
//
#include <hip/hip_runtime.h>
#include <stdint.h>

// 4-point Hermite resampler — barrier-free, wave-private LDS windows staged
// via global_load_lds, depth-3 channel pipeline with STORE-AWARE counted
// vmcnt. Per iter the vmem issue order is [2 loads][wait][compute][store];
// steady-state queue to KEEP is {S(s-3), L(s+1)x2, S(s-2), L(s+2)x2, S(s-1),
// L(s+3)x2} = 9 entries -> vmcnt(9); peeled prologue uses 6,7,8. Dead
// restages keep the count pattern uniform through the tail.
// WFL=320 floats/window (1.25 KB): 4 bufs x 4 waves = 20 KB LDS -> 8
// blocks/CU (100% occupancy), all 1882 blocks co-resident.
// Interior blocks read taps as p[-1..2] -> ds_read2_b32 pairs.
// Output stores are nontemporal so the 121 MB write stream doesn't evict y.

#define NW   4
#define OPW  256
#define TILE (NW * OPW)    // 1024 outputs per block
#define WFL  320           // staged floats per window (need <=285)
#define CPB  16            // channels per block (grid.y = 2)

typedef float vf4 __attribute__((ext_vector_type(4)));
typedef int   vi4 __attribute__((ext_vector_type(4)));

typedef const __attribute__((address_space(1))) uint32_t* gas_t;
typedef __attribute__((address_space(3))) uint32_t* las_t;

__device__ __forceinline__ void stage_win(const float* g, float* l, int lane) {
    // lane i: 16B from g+16i -> LDS l+16i (wave-uniform LDS base, linear)
    __builtin_amdgcn_global_load_lds((gas_t)g, (las_t)l, 16, 0, 0);
    if (lane < 16)   // prefix of lanes -> floats [256, 320)
        __builtin_amdgcn_global_load_lds((gas_t)(g + 256), (las_t)(l + 256), 16, 0, 0);
}

template<bool INTERIOR>
__device__ __forceinline__ void run(
    const float* __restrict__ gb, float* __restrict__ op, size_t chstride,
    int out_bs, float* b0, float* b1, float* b2, float* b3, int lane,
    const int* roff, const int* am1, const int* a1, const int* a2,
    vf4 xv, bool valid)
{
    stage_win(gb + 0 * chstride, b0, lane);
    stage_win(gb + 1 * chstride, b1, lane);
    stage_win(gb + 2 * chstride, b2, lane);

#define HBODY(S, CUR, NXT, CNT)                                               \
  {                                                                           \
    const int sn = ((S) + 3 < CPB) ? (S) + 3 : CPB - 1;  /* dead restage */   \
    stage_win(gb + (size_t)sn * chstride, NXT, lane);                         \
    asm volatile("s_waitcnt vmcnt(" #CNT ")" ::: "memory");                   \
    __builtin_amdgcn_sched_barrier(0);                                        \
    vf4 o;                                                                    \
    _Pragma("unroll")                                                         \
    for (int k = 0; k < 4; ++k) {                                             \
      float ym1, y0f, y1f, y2f;                                               \
      if (INTERIOR) {                                                         \
        const float* p = (CUR) + roff[k];                                     \
        ym1 = p[-1]; y0f = p[0]; y1f = p[1]; y2f = p[2];                      \
      } else {                                                                \
        ym1 = (CUR)[am1[k]]; y0f = (CUR)[roff[k]];                            \
        y1f = (CUR)[a1[k]];  y2f = (CUR)[a2[k]];                              \
      }                                                                       \
      const float c1 = 0.5f * (y1f - ym1);                                    \
      const float c2 = ym1 - 2.5f * y0f + 2.0f * y1f - 0.5f * y2f;            \
      const float c3 = 0.5f * (y2f - ym1) + 1.5f * (y0f - y1f);               \
      const float xw = xv[k];                                                 \
      o[k] = ((c3 * xw + c2) * xw + c1) * xw + y0f;                           \
    }                                                                         \
    if (valid)                                                                \
      __builtin_nontemporal_store(o, (vf4*)(op + (size_t)(S) * (size_t)out_bs)); \
  }

    HBODY(0, b0, b3, 6)
    HBODY(1, b1, b0, 7)
    HBODY(2, b2, b1, 8)
    HBODY(3, b3, b2, 9)
    for (int ss = 4; ss < CPB; ss += 4) {
        HBODY(ss + 0, b0, b3, 9)
        HBODY(ss + 1, b1, b0, 9)
        HBODY(ss + 2, b2, b1, 9)
        HBODY(ss + 3, b3, b2, 9)
    }
#undef HBODY
}

__global__ __launch_bounds__(256) void hermite_pipe_kernel(
    const float* __restrict__ y,       // [32, in_bs]
    const float* __restrict__ x,       // [out_bs]
    const int* __restrict__ y0_idx,    // [out_bs]
    float* __restrict__ out,           // [32, out_bs]
    int out_bs, int in_bs)
{
    __shared__ float sbuf[NW][4][WFL];   // 20 KB
    const int t    = threadIdx.x;
    const int w    = t >> 6;
    const int lane = t & 63;
    const int jw   = blockIdx.x * TILE + w * OPW;
    const int j    = jw + 4 * lane;
    const int ch0  = blockIdx.y * CPB;

    // wave-uniform window base, 16B-aligned, clamped so [src, src+WFL) is in-row
    int src = (y0_idx[min(jw, out_bs - 1)] - 1) & ~3;
    src = max(src, 0);
    src = min(src, in_bs - WFL);

    const bool valid = (j < out_bs);     // out_bs % 4 == 0
    vf4 xv  = {0.f, 0.f, 0.f, 0.f};
    vi4 y0v = {src + 1, src + 1, src + 1, src + 1};
    if (valid) {
        xv  = *(const vf4*)(x + j);
        y0v = *(const vi4*)(y0_idx + j);
    }

    int roff[4], am1[4], a1[4], a2[4];   // loop-invariant tap offsets
    #pragma unroll
    for (int k = 0; k < 4; ++k) {
        const int y0 = y0v[k];
        roff[k] = y0 - src;
        am1[k]  = max(y0 - 1, 0) - src;
        a1[k]   = min(y0 + 1, in_bs - 1) - src;
        a2[k]   = min(y0 + 2, in_bs - 1) - src;
    }

    const float* gb = y + (size_t)ch0 * (size_t)in_bs + src + 4 * lane;
    float*       op = out + (size_t)ch0 * (size_t)out_bs + j;
    float* b0 = &sbuf[w][0][0];
    float* b1 = &sbuf[w][1][0];
    float* b2 = &sbuf[w][2][0];
    float* b3 = &sbuf[w][3][0];

    // interior: no tap clamping possible, all p[-1..2] inside the window
    const bool interior = (src >= 4) && (src + WFL + 4 <= in_bs);
    if (interior)
        run<true >(gb, op, (size_t)in_bs, out_bs, b0, b1, b2, b3, lane,
                   roff, am1, a1, a2, xv, valid);
    else
        run<false>(gb, op, (size_t)in_bs, out_bs, b0, b1, b2, b3, lane,
                   roff, am1, a1, a2, xv, valid);
}

extern "C" void kernel_launch(void* const* d_in, const int* in_sizes, int n_in,
                              void* d_out, int out_size, void* d_ws, size_t ws_size,
                              hipStream_t stream)
{
    const float* y   = (const float*)d_in[0];
    const float* x   = (const float*)d_in[1];
    const int*   i0  = (const int*)d_in[3];   // y0_idx
    float*       out = (float*)d_out;

    const int out_bs = in_sizes[1];           // 963380
    const int n_ch   = out_size / out_bs;     // 32
    const int in_bs  = in_sizes[0] / n_ch;    // 1048576

    dim3 grid((out_bs + TILE - 1) / TILE, n_ch / CPB, 1);   // (941, 2)
    hermite_pipe_kernel<<<grid, 256, 0, stream>>>(
        y, x, i0, out, out_bs, in_bs);
}